// Round 7
// baseline (954.172 us; speedup 1.0000x reference)
//
#include <hip/hip_runtime.h>

// NAS-cell RNN, persistent kernel, XCD-local exchange, register-A MFMA, 8-wave WGs.
//   512 rows x 256 units x 256 steps. Grid 256 WGs x 512 thr (8 waves, 2/SIMD).
//   WG = (rowblock rb = blockIdx&15, 32 rows) x (unit group w = blockIdx>>4, 16 units).
//   Wave wv = (row-half rh = wv>>2) x (col-quarter cg = wv&3): 16 rows x 32 cols.
//   h exchanged as plain f16 slabs in d_ws; consumer waves load their MFMA A-frags
//   DIRECTLY from the slab (8x dwordx4/wave; 16B frag = row l15, k 8*lg4..+7): no LDS
//   h-staging, no DMA barrier. Freshness: 4 rotating slots (64KB) >> 32KB L1 evicts
//   stale lines; fast path hits the shared XCD L2 (co-location verified at startup,
//   agent/sc1 fallback otherwise). rec in registers as f16 hi/lo B-frags (K_eff=768,
//   h itself f16-only: absmax ~2e-3 vs 9.77e-3 threshold, validated R6).
//   Protocol (proven R5/R6): TCC-RMW poll + base-readback + memset'd flags.

#define NRB     16
#define RB_ROWS 32
#define WU      16
#define NSLOT   4
#define SLAB_BYTES (RB_ROWS*256*2)       // 16 KB per rowblock per slot
#define SLOT_BYTES (NRB*SLAB_BYTES)      // 256 KB per slot
#define SPIN_STEP 100000
#define SPIN_RDV  5000000

typedef _Float16 f16;
typedef f16  f16x8 __attribute__((ext_vector_type(8)));
typedef float f32x4 __attribute__((ext_vector_type(4)));
typedef unsigned int u32;
typedef unsigned long long u64;

__device__ __forceinline__ float sigm_(float xx) {
  float e = __expf(-xx);
  return __builtin_amdgcn_rcpf(1.0f + e);
}
__device__ __forceinline__ float tanh_(float xx) {
  float ax = __builtin_fabsf(xx);
  float e  = __expf(-2.0f * ax);
  float r  = (1.0f - e) * __builtin_amdgcn_rcpf(1.0f + e);
  return __builtin_copysignf(r, xx);
}

// Atomic RMW executes at the TCC (XCD L2): authoritative read regardless of L1.
__device__ __forceinline__ u32 rmw_add0_l2(u32* p) {
  u32 r, z = 0;
  asm volatile("global_atomic_add %0, %1, %2, off sc0\n\ts_waitcnt vmcnt(0)"
               : "=v"(r) : "v"(p), "v"(z) : "memory");
  return r;
}
__device__ __forceinline__ void inc_l2(u32* p, u32 v) {
  asm volatile("global_atomic_add %0, %1, off" :: "v"(p), "v"(v) : "memory");
}

__global__ __launch_bounds__(512, 2)
void nas_cell_rnn(const float* __restrict__ x,
                  const float* __restrict__ kern,
                  const float* __restrict__ rec,
                  float* __restrict__ out,
                  u32* __restrict__ ws32,
                  char* __restrict__ hbuf)
{
  const int tid  = threadIdx.x;
  const int lane = tid & 63;
  const int wv   = tid >> 6;        // wave 0..7
  const int rh   = wv >> 2;         // row-half 0..1 (rows rh*16..rh*16+15)
  const int cg   = wv & 3;          // col-quarter 0..3 (cols cg*32..cg*32+31)
  const int wg   = blockIdx.x;
  const int rb   = wg & 15;         // rowblock: members share blockIdx%8 (one XCD)
  const int w    = wg >> 4;         // unit group 0..15

  __shared__ float m_T[128][40];          // 20.5 KB transposed m (pitch 40: b128-aligned)
  __shared__ float x_lds[RB_ROWS][256];   // 32 KB
  __shared__ u32   fast_s;

  const int l15 = lane & 15;
  const int lg4 = lane >> 4;

  u32* const pcnt = ws32 + 288 + rb*32;   // 128B-strided per-rowblock flag

  // ---- rendezvous: publish XCC id, verify co-location, read flag base ----
  u32 xcc;
  asm("s_getreg_b32 %0, hwreg(HW_REG_XCC_ID)" : "=s"(xcc));
  u32 base = 0;
  if (tid == 0) {
    __hip_atomic_store(&ws32[wg], xcc, __ATOMIC_RELAXED, __HIP_MEMORY_SCOPE_AGENT);
    __hip_atomic_fetch_add(&ws32[256], 1u, __ATOMIC_RELEASE, __HIP_MEMORY_SCOPE_AGENT);
    int sp = 0;
    while (__hip_atomic_load(&ws32[256], __ATOMIC_RELAXED, __HIP_MEMORY_SCOPE_AGENT) < 256u)
      if (++sp > SPIN_RDV) break;
    u32 ok = 1;
    for (int w2 = 0; w2 < 16; ++w2) {
      u32 o = __hip_atomic_load(&ws32[w2*16 + rb], __ATOMIC_RELAXED, __HIP_MEMORY_SCOPE_AGENT);
      ok &= (o == xcc) ? 1u : 0u;
    }
    fast_s = ok;
    // base-readback MUST precede any increment of this launch (phase-2 guards)
    base = ok ? rmw_add0_l2(pcnt)
              : __hip_atomic_load(pcnt, __ATOMIC_RELAXED, __HIP_MEMORY_SCOPE_AGENT);
    __hip_atomic_fetch_add(&ws32[260], 1u, __ATOMIC_RELEASE, __HIP_MEMORY_SCOPE_AGENT);
    sp = 0;
    while (__hip_atomic_load(&ws32[260], __ATOMIC_RELAXED, __HIP_MEMORY_SCOPE_AGENT) < 256u)
      if (++sp > SPIN_RDV) break;
  }
  __syncthreads();
  const bool fast = (fast_s != 0);

  // ---- one-time: rec slice -> register B-fragments, hi (pl=0) and lo (pl=1) ----
  f16x8 bfr[2][2][8];                 // [col-tile ci][plane][k-chunk sb]
#pragma unroll
  for (int ci = 0; ci < 2; ++ci) {
    const int colidx = cg*32 + ci*16 + l15;     // 0..127 within WG
    const int gate   = colidx >> 4;
    const int ucol   = colidx & 15;
    const int gcol   = gate*256 + w*WU + ucol;  // column in rec [256][2048]
#pragma unroll
    for (int sb = 0; sb < 8; ++sb) {
      f16x8 vh, vl;
#pragma unroll
      for (int e = 0; e < 8; ++e) {
        const int k = 32*sb + 8*lg4 + e;        // B-frag: k = 8*(lane>>4)+e, col = lane&15
        const float r = rec[k*2048 + gcol];
        const f16 hi = (f16)r;
        vh[e] = hi;
        vl[e] = (f16)(r - (float)hi);
      }
      bfr[ci][0][sb] = vh;
      bfr[ci][1][sb] = vl;
    }
  }

  // ---- one-time: x rows -> LDS ----
  {
    const float4* src = (const float4*)(x + (size_t)rb*RB_ROWS*256);
    float4* dst = (float4*)&x_lds[0][0];
#pragma unroll
    for (int i = 0; i < 4; ++i) dst[tid + 512*i] = src[tid + 512*i];
  }

  const int ul = tid & 15;            // unit within group
  const int b  = tid >> 4;            // row 0..31: exactly one cell per thread
  float kv[8];
#pragma unroll
  for (int g = 0; g < 8; ++g) kv[g] = kern[g*256 + w*WU + ul];

  float cst = 0.0f;
  int sr = 0, sw = 1;                 // read/write slot ids

  char* const hrb = hbuf + (size_t)rb * SLAB_BYTES;   // rowblock slab within a slot

  for (int t = 0; t < 256; ++t) {
    // ================= wait + A-frags from L2 + MFMA =================
    if (t > 0) {
      if (tid == 0) {
        const u32 tgt = base + 16u * (u32)t;
        int sp = 0;
        if (fast) {
          while (rmw_add0_l2(pcnt) < tgt)              // TCC-authoritative poll
            if (++sp > SPIN_STEP) break;
        } else {
          while (__hip_atomic_load(pcnt, __ATOMIC_RELAXED,
                                   __HIP_MEMORY_SCOPE_AGENT) < tgt)   // LLC poll
            if (++sp > SPIN_STEP) break;
        }
      }
      __syncthreads();    // release all waves; ordering point
      __builtin_amdgcn_sched_barrier(0);

      // A-fragments straight from the h-slab: row rh*16+l15, 16B at k = 32sb+8lg4
      const char* arow = hrb + (size_t)sr * SLOT_BYTES + (size_t)(rh*16 + l15) * 512
                       + lg4*16;
      f16x8 a[8];
      if (fast) {
#pragma unroll
        for (int sb = 0; sb < 8; ++sb)
          a[sb] = *(const f16x8*)(arow + sb*64);       // plain dwordx4, L1-fresh by
                                                       // slot rotation (64KB >> L1)
      } else {
#pragma unroll
        for (int sb = 0; sb < 8; ++sb) {
          const u64* p = (const u64*)(arow + sb*64);
          const u64 lo = __hip_atomic_load(p,     __ATOMIC_RELAXED, __HIP_MEMORY_SCOPE_AGENT);
          const u64 hi = __hip_atomic_load(p + 1, __ATOMIC_RELAXED, __HIP_MEMORY_SCOPE_AGENT);
          union { u64 q[2]; f16x8 v; } u2; u2.q[0] = lo; u2.q[1] = hi;
          a[sb] = u2.v;
        }
      }

      f32x4 acc0 = {0,0,0,0}, acc1 = {0,0,0,0};
#pragma unroll
      for (int sb = 0; sb < 8; ++sb) {
        acc0 = __builtin_amdgcn_mfma_f32_16x16x32_f16(a[sb], bfr[0][0][sb], acc0, 0, 0, 0);
        acc1 = __builtin_amdgcn_mfma_f32_16x16x32_f16(a[sb], bfr[1][0][sb], acc1, 0, 0, 0);
        acc0 = __builtin_amdgcn_mfma_f32_16x16x32_f16(a[sb], bfr[0][1][sb], acc0, 0, 0, 0);
        acc1 = __builtin_amdgcn_mfma_f32_16x16x32_f16(a[sb], bfr[1][1][sb], acc1, 0, 0, 0);
      }
      // C layout: col = lane&15, row = 4*(lane>>4)+j -> m_T[col][row], b128 writes
      *(f32x4*)&m_T[cg*32      + l15][rh*16 + 4*lg4] = acc0;
      *(f32x4*)&m_T[cg*32 + 16 + l15][rh*16 + 4*lg4] = acc1;
    }
    __syncthreads();

    // ================= elementwise NAS cell: 1 cell/thread =================
    {
      const float xv = x_lds[b][t];
      float mg[8];
#pragma unroll
      for (int g = 0; g < 8; ++g)
        mg[g] = (t == 0) ? 0.0f : m_T[g*WU + ul][b];

      const float i0 = xv*kv[0], i1 = xv*kv[1], i2 = xv*kv[2], i3 = xv*kv[3];
      const float i4 = xv*kv[4], i5 = xv*kv[5], i6 = xv*kv[6], i7 = xv*kv[7];

      const float l1_0 = sigm_(i0 + mg[0]);
      const float l1_1 = fmaxf(i1 + mg[1], 0.0f);
      const float l1_2 = sigm_(i2 + mg[2]);
      const float l1_3 = fmaxf(i3 * mg[3], 0.0f);
      const float l1_4 = tanh_(i4 + mg[4]);
      const float l1_5 = sigm_(i5 + mg[5]);
      const float l1_6 = tanh_(i6 + mg[6]);
      const float l1_7 = sigm_(i7 + mg[7]);

      float       l2_0 = tanh_(l1_0 * l1_1);
      const float l2_1 = tanh_(l1_2 + l1_3);
      const float l2_2 = tanh_(l1_4 * l1_5);
      const float l2_3 = sigm_(l1_6 + l1_7);

      l2_0 = tanh_(l2_0 + cst);
      const float nc = l2_0 * l2_1;
      const float l3 = tanh_(l2_2 + l2_3);
      const float nh = tanh_(nc * l3);
      cst = nc;

      if (t == 255) {
        out[(rb*RB_ROWS + b)*256 + w*WU + ul] = nh;
      } else {
        f16* dst = (f16*)(hrb + (size_t)sw * SLOT_BYTES) + (b*256 + w*WU + ul);
        if (fast) {
          *dst = (f16)nh;             // plain store: write-through to shared XCD L2
        } else {
          unsigned short us = __builtin_bit_cast(unsigned short, (f16)nh);
          __hip_atomic_store((unsigned short*)dst, us,
                             __ATOMIC_RELAXED, __HIP_MEMORY_SCOPE_AGENT);
        }
      }
    }
    asm volatile("s_waitcnt vmcnt(0)" ::: "memory");   // own h stores in L2
    __syncthreads();                                   // => all 8 waves' stores done

    if (t < 255 && tid == 0) {
      if (fast) inc_l2(pcnt, 1u);                      // RMW at local TCC
      else __hip_atomic_fetch_add(pcnt, 1u, __ATOMIC_RELAXED, __HIP_MEMORY_SCOPE_AGENT);
    }
    sr = sw; sw = (sw == NSLOT-1) ? 0 : sw + 1;
  }
}

extern "C" void kernel_launch(void* const* d_in, const int* in_sizes, int n_in,
                              void* d_out, int out_size, void* d_ws, size_t ws_size,
                              hipStream_t stream) {
  (void)in_sizes; (void)n_in; (void)out_size; (void)ws_size;
  const float* x    = (const float*)d_in[0];   // [512, 256]
  const float* kern = (const float*)d_in[1];   // [1, 2048]
  const float* rec  = (const float*)d_in[2];   // [256, 2048]
  float* out = (float*)d_out;                  // [512, 256]

  u32*  ws32 = (u32*)d_ws;   // [0..255] xcc ids, [256] ph1, [260] ph2, 288+rb*32 flags
  char* hbuf = (char*)d_ws + 4096;             // 4 slots x 256 KB

  hipMemsetAsync(d_ws, 0, 4096, stream);
  hipLaunchKernelGGL(nas_cell_rnn, dim3(256), dim3(512), 0, stream,
                     x, kern, rec, out, ws32, hbuf);
}